// Round 4
// baseline (301.154 us; speedup 1.0000x reference)
//
#include <hip/hip_runtime.h>

typedef __attribute__((ext_vector_type(8))) short short8;
typedef __attribute__((ext_vector_type(4))) float f32x4;

#define DEV __device__ __forceinline__

// ---------- helpers ----------
DEV unsigned short f2bf(float f) {
    unsigned int u = __float_as_uint(f);
    u += 0x7FFFu + ((u >> 16) & 1u);   // round-to-nearest-even
    return (unsigned short)(u >> 16);
}
DEV float bf2f(unsigned short h) { return __uint_as_float(((unsigned int)h) << 16); }

DEV void gload16(const void* g, void* l) {
    __builtin_amdgcn_global_load_lds(
        (const __attribute__((address_space(1))) void*)(unsigned long long)g,
        (__attribute__((address_space(3))) void*)(unsigned int)(unsigned long long)l,
        16, 0, 0);
}

// ---------- cast f32 -> bf16, 8 elems/thread ----------
__global__ void cast_bf16_kernel(const float* __restrict__ in, unsigned short* __restrict__ out, int n8) {
    int gid = blockIdx.x * 256 + threadIdx.x;
    if (gid >= n8) return;
    const f32x4* p = (const f32x4*)in + (size_t)gid * 2;
    f32x4 a = p[0], b = p[1];
    short8 v;
    v[0] = (short)f2bf(a[0]); v[1] = (short)f2bf(a[1]); v[2] = (short)f2bf(a[2]); v[3] = (short)f2bf(a[3]);
    v[4] = (short)f2bf(b[0]); v[5] = (short)f2bf(b[1]); v[6] = (short)f2bf(b[2]); v[7] = (short)f2bf(b[3]);
    *(short8*)(out + (size_t)gid * 8) = v;
}

// ---------- cast 4 weights (each 1M floats) in one dispatch ----------
__global__ void cast_w4_kernel(const float* __restrict__ w0, const float* __restrict__ w1,
                               const float* __restrict__ w2, const float* __restrict__ w3,
                               unsigned short* __restrict__ o0, unsigned short* __restrict__ o1,
                               unsigned short* __restrict__ o2, unsigned short* __restrict__ o3) {
    int gid = blockIdx.x * 256 + threadIdx.x;  // 4 * 131072
    int sel = gid >> 17, idx = gid & 131071;
    const float* in = (sel == 0) ? w0 : (sel == 1) ? w1 : (sel == 2) ? w2 : w3;
    unsigned short* out = (sel == 0) ? o0 : (sel == 1) ? o1 : (sel == 2) ? o2 : o3;
    const f32x4* p = (const f32x4*)in + (size_t)idx * 2;
    f32x4 a = p[0], b = p[1];
    short8 v;
    v[0] = (short)f2bf(a[0]); v[1] = (short)f2bf(a[1]); v[2] = (short)f2bf(a[2]); v[3] = (short)f2bf(a[3]);
    v[4] = (short)f2bf(b[0]); v[5] = (short)f2bf(b[1]); v[6] = (short)f2bf(b[2]); v[7] = (short)f2bf(b[3]);
    *(short8*)(out + (size_t)idx * 8) = v;
}

// ---------- RoPE tables: cos/sin (256 x 32) ----------
__global__ void rope_table_kernel(float* __restrict__ cosT, float* __restrict__ sinT) {
    int gid = blockIdx.x * 256 + threadIdx.x;
    if (gid >= 256 * 32) return;
    int s = gid >> 5, i = gid & 31;
    float inv = powf(10000.0f, -(float)i * (1.0f / 32.0f));
    float f = (float)s * inv;
    cosT[gid] = cosf(f);
    sinT[gid] = sinf(f);
}

// =====================================================================
// 256x256 tile, BK=32, 8 waves (2x4), 512 threads, 4 LDS buffers (128KB).
// Each K-tile = TWO 16-MFMA phases:
//   { issue ds_reads + 1 half stage -> sched_barrier -> NAKED s_barrier ->
//     lgkmcnt(0)+sched_barrier -> setprio(1) 16 MFMA setprio(0) ->
//     sched_barrier -> NAKED s_barrier }
// Stage lead = 2 tiles (ring buf (t+2)&3), counted vmcnt(4) once per tile.
// ds_reads stay in flight ACROSS the naked barrier; each wave blocks only
// on its own lgkmcnt -> staggered MFMA start, LDS service overlaps MFMA.
// MODE 0: N=3072 (Wq|Wk|Wv); RoPE fused; scatters q,k:(B,H,S,64),
//         vt:(B,H,64,S) bf16.   MODE 1: N=1024 (Wo); f32 row-major out.
// =====================================================================
#define NT 32  // K=1024 / 32

#define RD16(ARR, OFF) (*(const short8*)&(ARR)[OFF])

#define STG(DST, BASEP, TS) do {                                               \
    int ts_ = (TS) < NT ? (TS) : (NT - 1);                                     \
    const unsigned short* sp_ = (BASEP) + (size_t)ts_ * 32;                    \
    gload16(sp_ + rel0, &(DST)[(size_t)tid * 8]);                              \
    gload16(sp_ + rel1, &(DST)[(size_t)(tid + 512) * 8]);                      \
} while (0)

#define MM4(MI, A) do {                                                        \
    acc[MI][0] = __builtin_amdgcn_mfma_f32_16x16x32_bf16(A, bv[0], acc[MI][0], 0, 0, 0); \
    acc[MI][1] = __builtin_amdgcn_mfma_f32_16x16x32_bf16(A, bv[1], acc[MI][1], 0, 0, 0); \
    acc[MI][2] = __builtin_amdgcn_mfma_f32_16x16x32_bf16(A, bv[2], acc[MI][2], 0, 0, 0); \
    acc[MI][3] = __builtin_amdgcn_mfma_f32_16x16x32_bf16(A, bv[3], acc[MI][3], 0, 0, 0); \
} while (0)

#define PHA(BUF, SBUF, TS) do {                                                \
    short8 a0 = RD16(Al[BUF], aoff[0]);                                        \
    short8 a1 = RD16(Al[BUF], aoff[1]);                                        \
    short8 a2 = RD16(Al[BUF], aoff[2]);                                        \
    short8 a3 = RD16(Al[BUF], aoff[3]);                                        \
    bv[0] = RD16(Bl[BUF], boff[0]);                                            \
    bv[1] = RD16(Bl[BUF], boff[1]);                                            \
    bv[2] = RD16(Bl[BUF], boff[2]);                                            \
    bv[3] = RD16(Bl[BUF], boff[3]);                                            \
    STG(Al[SBUF], Abase, TS);                                                  \
    __builtin_amdgcn_sched_barrier(0);                                         \
    __builtin_amdgcn_s_barrier();                                              \
    asm volatile("s_waitcnt lgkmcnt(0)" ::: "memory");                         \
    __builtin_amdgcn_sched_barrier(0);                                         \
    __builtin_amdgcn_s_setprio(1);                                             \
    MM4(0, a0); MM4(1, a1); MM4(2, a2); MM4(3, a3);                            \
    __builtin_amdgcn_s_setprio(0);                                             \
    __builtin_amdgcn_sched_barrier(0);                                         \
    __builtin_amdgcn_s_barrier();                                              \
} while (0)

#define PHB(BUF, SBUF, TS) do {                                                \
    short8 a4 = RD16(Al[BUF], aoff[4]);                                        \
    short8 a5 = RD16(Al[BUF], aoff[5]);                                        \
    short8 a6 = RD16(Al[BUF], aoff[6]);                                        \
    short8 a7 = RD16(Al[BUF], aoff[7]);                                        \
    STG(Bl[SBUF], Bbase, TS);                                                  \
    __builtin_amdgcn_sched_barrier(0);                                         \
    __builtin_amdgcn_s_barrier();                                              \
    asm volatile("s_waitcnt lgkmcnt(0)" ::: "memory");                         \
    __builtin_amdgcn_sched_barrier(0);                                         \
    __builtin_amdgcn_s_setprio(1);                                             \
    MM4(4, a4); MM4(5, a5); MM4(6, a6); MM4(7, a7);                            \
    __builtin_amdgcn_s_setprio(0);                                             \
    asm volatile("s_waitcnt vmcnt(4)" ::: "memory");                           \
    __builtin_amdgcn_sched_barrier(0);                                         \
    __builtin_amdgcn_s_barrier();                                              \
} while (0)

template <int MODE>
__global__ __launch_bounds__(512, 2) void gemm256_kernel(
    const unsigned short* __restrict__ A,
    const unsigned short* __restrict__ W0,
    const unsigned short* __restrict__ W1,
    const unsigned short* __restrict__ W2,
    unsigned short* __restrict__ q,
    unsigned short* __restrict__ k,
    unsigned short* __restrict__ vt,
    float* __restrict__ outF,
    const float* __restrict__ cosT,
    const float* __restrict__ sinT)
{
    __shared__ __align__(16) unsigned short Al[4][8192];  // 4 x 16KB (256 rows x 32 K)
    __shared__ __align__(16) unsigned short Bl[4][8192];  // 4 x 16KB

    const int tid = threadIdx.x;
    const int l = tid & 63;
    const int w = tid >> 6;
    const int wr = w >> 2, wc = w & 3;
    const int l15 = l & 15, lg = l >> 4;

    // XCD-aware block swizzle (grid % 8 == 0 for both modes)
    const int nwg = gridDim.x;
    const int bid = blockIdx.x;
    const int cpx = nwg >> 3;
    const int swz = (bid & 7) * cpx + (bid >> 3);
    const int NBX = (MODE == 0) ? 12 : 4;
    const int bx = swz % NBX, by = swz / NBX;
    const int m0 = by * 256, n0 = bx * 256;

    const unsigned short* Bp;
    int nb, sel = 0;
    if (MODE == 0) {
        sel = n0 >> 10;
        Bp = (sel == 0) ? W0 : ((sel == 1) ? W1 : W2);
        nb = n0 & 1023;
    } else {
        Bp = W0;
        nb = n0;
    }

    // stage source offsets (inverse-swizzled source; linear LDS dest)
    const int f0 = tid, f1 = tid + 512;
    const int rel0 = (f0 >> 2) * 1024 + (((f0 & 3) ^ ((f0 >> 3) & 3)) * 8);
    const int rel1 = (f1 >> 2) * 1024 + (((f1 & 3) ^ ((f1 >> 3) & 3)) * 8);
    const unsigned short* Abase = A + (size_t)m0 * 1024;
    const unsigned short* Bbase = Bp + (size_t)nb * 1024;

    // swizzled LDS read offsets (ushort units)
    int aoff[8], boff[4];
#pragma unroll
    for (int mi = 0; mi < 8; ++mi) {
        int row = wr * 128 + mi * 16 + l15;
        aoff[mi] = row * 32 + ((lg ^ ((row >> 1) & 3)) * 8);
    }
#pragma unroll
    for (int ni = 0; ni < 4; ++ni) {
        int row = wc * 64 + ni * 16 + l15;
        boff[ni] = row * 32 + ((lg ^ ((row >> 1) & 3)) * 8);
    }

    f32x4 acc[8][4];
#pragma unroll
    for (int mi = 0; mi < 8; ++mi)
#pragma unroll
        for (int ni = 0; ni < 4; ++ni)
#pragma unroll
            for (int e = 0; e < 4; ++e) acc[mi][ni][e] = 0.f;

    short8 bv[4];

    // prologue: stage tiles 0,1 (8 gloads); wait tile 0 (leave tile 1 in flight)
    STG(Al[0], Abase, 0); STG(Bl[0], Bbase, 0);
    STG(Al[1], Abase, 1); STG(Bl[1], Bbase, 1);
    asm volatile("s_waitcnt vmcnt(4)" ::: "memory");
    __builtin_amdgcn_sched_barrier(0);
    __builtin_amdgcn_s_barrier();

#pragma unroll 1
    for (int it = 0; it < NT / 4; ++it) {
        const int t0 = it * 4;
        PHA(0, 2, t0 + 2); PHB(0, 2, t0 + 2);
        PHA(1, 3, t0 + 3); PHB(1, 3, t0 + 3);
        PHA(2, 0, t0 + 4); PHB(2, 0, t0 + 4);
        PHA(3, 1, t0 + 5); PHB(3, 1, t0 + 5);
    }

    // ---------------- epilogue ----------------
    if (MODE == 0) {
#pragma unroll
        for (int mi = 0; mi < 8; ++mi) {
#pragma unroll
            for (int i = 0; i < 4; ++i) {
                int grow = m0 + wr * 128 + mi * 16 + lg * 4 + i;
                int b = grow >> 8, s = grow & 255;
                if (sel < 2) {
                    // RoPE: pair (d, d+32) = (acc[..][ni], acc[..][ni+2]), d = ni*16+l15
#pragma unroll
                    for (int ni = 0; ni < 2; ++ni) {
                        int d = ni * 16 + l15;
                        float c = cosT[s * 32 + d], sn = sinT[s * 32 + d];
                        float lo = acc[mi][ni][i], hi = acc[mi][ni + 2][i];
                        acc[mi][ni][i] = lo * c - hi * sn;
                        acc[mi][ni + 2][i] = hi * c + lo * sn;
                    }
                }
#pragma unroll
                for (int ni = 0; ni < 4; ++ni) {
                    int col = n0 + wc * 64 + ni * 16 + l15;
                    int cc = col & 1023;
                    int h = cc >> 6, d = cc & 63;
                    unsigned short v = f2bf(acc[mi][ni][i]);
                    if (sel == 0)
                        q[((size_t)(b * 16 + h) * 256 + s) * 64 + d] = v;
                    else if (sel == 1)
                        k[((size_t)(b * 16 + h) * 256 + s) * 64 + d] = v;
                    else
                        vt[((size_t)(b * 16 + h) * 64 + d) * 256 + s] = v;
                }
            }
        }
    } else {
#pragma unroll
        for (int mi = 0; mi < 8; ++mi) {
#pragma unroll
            for (int i = 0; i < 4; ++i) {
                int grow = m0 + wr * 128 + mi * 16 + lg * 4 + i;
#pragma unroll
                for (int ni = 0; ni < 4; ++ni) {
                    int col = n0 + wc * 64 + ni * 16 + l15;
                    outF[(size_t)grow * 1024 + col] = acc[mi][ni][i];
                }
            }
        }
    }
}

// ---------- fused attention per (b,h): 8 waves x 32 q-rows, online softmax ----------
__global__ __launch_bounds__(512) void attn_kernel(
    const unsigned short* __restrict__ qp,   // (B,H,S,64) bf16, RoPE'd
    const unsigned short* __restrict__ kp,   // (B,H,S,64) bf16, RoPE'd
    const unsigned short* __restrict__ vtp,  // (B,H,64,S) bf16
    const int* __restrict__ mask,            // (B,S)
    unsigned short* __restrict__ ao)         // (B,S,1024) bf16
{
    __shared__ __align__(16) unsigned short Ks[128 * 64];    // [key 0..127][d 0..63], swizzled 128B rows
    __shared__ __align__(16) unsigned short Vts[64 * 128];   // [d 0..63][key 0..127], swizzled 256B rows
    __shared__ __align__(16) unsigned short Ps[8][32 * 64];  // per-wave P, swizzled 128B rows

    const int bh = blockIdx.x;
    const int b = bh >> 4, h = bh & 15;
    const int tid = threadIdx.x;
    const int l = tid & 63, w = tid >> 6;
    const int l15 = l & 15, lg = l >> 4;

    const unsigned short* kbase = kp + (size_t)bh * (256 * 64);
    const unsigned short* vtbase = vtp + (size_t)bh * (64 * 256);
    const unsigned short* qbase = qp + (size_t)bh * (256 * 64) + (size_t)(w * 32) * 64;

    short8 aq[2][2];
#pragma unroll
    for (int m = 0; m < 2; ++m)
#pragma unroll
        for (int ks = 0; ks < 2; ++ks)
            aq[m][ks] = *(const short8*)(qbase + (m * 16 + l15) * 64 + ks * 32 + lg * 8);

    float m_run[2][4], l_run[2][4];
    f32x4 o[2][4];
#pragma unroll
    for (int m = 0; m < 2; ++m)
#pragma unroll
        for (int i = 0; i < 4; ++i) { m_run[m][i] = -3.0e38f; l_run[m][i] = 0.f; }
#pragma unroll
    for (int m = 0; m < 2; ++m)
#pragma unroll
        for (int n = 0; n < 4; ++n)
#pragma unroll
            for (int e = 0; e < 4; ++e) o[m][n][e] = 0.f;

    const int* mrow = mask + b * 256;

    for (int half = 0; half < 2; ++half) {
        __syncthreads();
        for (int c2 = tid; c2 < 1024; c2 += 512) {
            int off = c2 * 16;
            int row = off >> 7, cb = off & 127;
            short8 v = *(const short8*)((const char*)kbase + (size_t)half * 16384 + off);
            *(short8*)((char*)Ks + row * 128 + (cb ^ ((row & 7) << 4))) = v;
        }
        for (int c2 = tid; c2 < 1024; c2 += 512) {
            int off = c2 * 16;
            int row = off >> 8, cb = off & 255;
            short8 v = *(const short8*)((const char*)vtbase + (size_t)row * 512 + half * 256 + cb);
            *(short8*)((char*)Vts + row * 256 + (cb ^ ((row & 7) << 4))) = v;
        }
        __syncthreads();

        for (int t2 = 0; t2 < 2; ++t2) {
            const int keyl = t2 * 64;
            const int keyg = half * 128 + keyl;

            f32x4 sf[2][4];
#pragma unroll
            for (int m = 0; m < 2; ++m)
#pragma unroll
                for (int n = 0; n < 4; ++n)
#pragma unroll
                    for (int e = 0; e < 4; ++e) sf[m][n][e] = 0.f;
#pragma unroll
            for (int ks = 0; ks < 2; ++ks) {
                short8 bk[4];
#pragma unroll
                for (int n = 0; n < 4; ++n) {
                    int row = keyl + n * 16 + l15;
                    int cb = (ks * 64 + lg * 16) ^ ((row & 7) << 4);
                    bk[n] = *(const short8*)((char*)Ks + row * 128 + cb);
                }
#pragma unroll
                for (int m = 0; m < 2; ++m)
#pragma unroll
                    for (int n = 0; n < 4; ++n)
                        sf[m][n] = __builtin_amdgcn_mfma_f32_16x16x32_bf16(aq[m][ks], bk[n], sf[m][n], 0, 0, 0);
            }
            float madd[4];
#pragma unroll
            for (int n = 0; n < 4; ++n) madd[n] = mrow[keyg + n * 16 + l15] ? 0.f : -1e30f;
#pragma unroll
            for (int m = 0; m < 2; ++m)
#pragma unroll
                for (int n = 0; n < 4; ++n)
#pragma unroll
                    for (int i = 0; i < 4; ++i) sf[m][n][i] = sf[m][n][i] * 0.125f + madd[n];
            float al[2][4];
#pragma unroll
            for (int m = 0; m < 2; ++m)
#pragma unroll
                for (int i = 0; i < 4; ++i) {
                    float mx = fmaxf(fmaxf(sf[m][0][i], sf[m][1][i]), fmaxf(sf[m][2][i], sf[m][3][i]));
                    mx = fmaxf(mx, __shfl_xor(mx, 1));
                    mx = fmaxf(mx, __shfl_xor(mx, 2));
                    mx = fmaxf(mx, __shfl_xor(mx, 4));
                    mx = fmaxf(mx, __shfl_xor(mx, 8));
                    float mnew = fmaxf(m_run[m][i], mx);
                    al[m][i] = __expf(m_run[m][i] - mnew);
                    m_run[m][i] = mnew;
                }
            float rs[2][4];
#pragma unroll
            for (int m = 0; m < 2; ++m)
#pragma unroll
                for (int i = 0; i < 4; ++i) rs[m][i] = 0.f;
#pragma unroll
            for (int m = 0; m < 2; ++m)
#pragma unroll
                for (int n = 0; n < 4; ++n)
#pragma unroll
                    for (int i = 0; i < 4; ++i) {
                        float p = __expf(sf[m][n][i] - m_run[m][i]);
                        sf[m][n][i] = p;
                        rs[m][i] += p;
                    }
#pragma unroll
            for (int m = 0; m < 2; ++m)
#pragma unroll
                for (int i = 0; i < 4; ++i) {
                    float r2 = rs[m][i];
                    r2 += __shfl_xor(r2, 1);
                    r2 += __shfl_xor(r2, 2);
                    r2 += __shfl_xor(r2, 4);
                    r2 += __shfl_xor(r2, 8);
                    l_run[m][i] = l_run[m][i] * al[m][i] + r2;
                }
#pragma unroll
            for (int m = 0; m < 2; ++m)
#pragma unroll
                for (int n = 0; n < 4; ++n)
#pragma unroll
                    for (int i = 0; i < 4; ++i) o[m][n][i] *= al[m][i];

            __syncthreads();
#pragma unroll
            for (int m = 0; m < 2; ++m)
#pragma unroll
                for (int n = 0; n < 4; ++n)
#pragma unroll
                    for (int i = 0; i < 4; ++i) {
                        int row = m * 16 + lg * 4 + i;
                        int cb = ((n * 16 + l15) * 2) ^ ((row & 7) << 4);
                        *(unsigned short*)((char*)Ps[w] + row * 128 + cb) = f2bf(sf[m][n][i]);
                    }
            __syncthreads();
#pragma unroll
            for (int ks = 0; ks < 2; ++ks) {
                short8 pa[2];
#pragma unroll
                for (int m = 0; m < 2; ++m) {
                    int row = m * 16 + l15;
                    int cb = (ks * 64 + lg * 16) ^ ((row & 7) << 4);
                    pa[m] = *(const short8*)((char*)Ps[w] + row * 128 + cb);
                }
                short8 vb[4];
#pragma unroll
                for (int n = 0; n < 4; ++n) {
                    int row = n * 16 + l15;
                    int cb = (keyl * 2 + ks * 64 + lg * 16) ^ ((row & 7) << 4);
                    vb[n] = *(const short8*)((char*)Vts + row * 256 + cb);
                }
#pragma unroll
                for (int m = 0; m < 2; ++m)
#pragma unroll
                    for (int n = 0; n < 4; ++n)
                        o[m][n] = __builtin_amdgcn_mfma_f32_16x16x32_bf16(pa[m], vb[n], o[m][n], 0, 0, 0);
            }
        }
    }

    unsigned short* aop = ao + ((size_t)(b * 256 + w * 32)) * 1024 + h * 64;
#pragma unroll
    for (int m = 0; m < 2; ++m)
#pragma unroll
        for (int n = 0; n < 4; ++n)
#pragma unroll
            for (int i = 0; i < 4; ++i) {
                int row = m * 16 + lg * 4 + i;
                int d = n * 16 + l15;
                aop[(size_t)row * 1024 + d] = f2bf(o[m][n][i] / l_run[m][i]);
            }
}

// ---------- launch ----------
extern "C" void kernel_launch(void* const* d_in, const int* in_sizes, int n_in,
                              void* d_out, int out_size, void* d_ws, size_t ws_size,
                              hipStream_t stream) {
    const float* x = (const float*)d_in[0];
    const int* mask = (const int*)d_in[1];
    const float* Wq = (const float*)d_in[2];
    const float* Wk = (const float*)d_in[3];
    const float* Wv = (const float*)d_in[4];
    const float* Wo = (const float*)d_in[5];
    float* out = (float*)d_out;

    char* ws = (char*)d_ws;
    size_t off = 0;
    auto alloc = [&](size_t bytes) -> char* {
        char* p = ws + off;
        off = (off + bytes + 255) & ~(size_t)255;
        return p;
    };
    unsigned short* xb = (unsigned short*)alloc((size_t)16384 * 1024 * 2);  // bf16 x; later aliased as attn_out
    unsigned short* wqb = (unsigned short*)alloc((size_t)1024 * 1024 * 2);
    unsigned short* wkb = (unsigned short*)alloc((size_t)1024 * 1024 * 2);
    unsigned short* wvb = (unsigned short*)alloc((size_t)1024 * 1024 * 2);
    unsigned short* wob = (unsigned short*)alloc((size_t)1024 * 1024 * 2);
    unsigned short* q = (unsigned short*)alloc((size_t)16384 * 1024 * 2);   // (B,H,S,64)
    unsigned short* k = (unsigned short*)alloc((size_t)16384 * 1024 * 2);   // (B,H,S,64)
    unsigned short* vt = (unsigned short*)alloc((size_t)16384 * 1024 * 2);  // (B,H,64,S)
    float* cosT = (float*)alloc(256 * 32 * 4);
    float* sinT = (float*)alloc(256 * 32 * 4);

    cast_bf16_kernel<<<16777216 / 8 / 256, 256, 0, stream>>>(x, xb, 16777216 / 8);
    cast_w4_kernel<<<4 * 131072 / 256, 256, 0, stream>>>(Wq, Wk, Wv, Wo, wqb, wkb, wvb, wob);
    rope_table_kernel<<<32, 256, 0, stream>>>(cosT, sinT);

    gemm256_kernel<0><<<768, 512, 0, stream>>>(xb, wqb, wkb, wvb, q, k, vt, nullptr, cosT, sinT);
    attn_kernel<<<1024, 512, 0, stream>>>(q, k, vt, mask, xb /* attn_out, aliases xb */);
    gemm256_kernel<1><<<256, 512, 0, stream>>>(xb, wob, nullptr, nullptr, nullptr, nullptr, nullptr, out, nullptr, nullptr);

    (void)in_sizes; (void)n_in; (void)out_size; (void)ws_size;
}